// Round 14
// baseline (212.753 us; speedup 1.0000x reference)
//
#include <hip/hip_runtime.h>
#include <hip/hip_bf16.h>

#define T_ 8
#define H_ 96
#define W_ 160
#define C_ 256
#define F_ 256
#define M_ (T_ * H_ * W_)   // 122880

typedef __bf16 bf16_t;
typedef __bf16 bf16x4 __attribute__((ext_vector_type(4)));
typedef __bf16 bf16x8 __attribute__((ext_vector_type(8)));
typedef float  f32x4  __attribute__((ext_vector_type(4)));

// ---------------- pass 0: WpT[f][c] = bf16(Wp[c][f]) ----------------
__global__ void wp_transpose_kernel(const float* __restrict__ Wp,
                                    bf16_t* __restrict__ WpT) {
    int c = blockIdx.x;   // 0..255
    int f = threadIdx.x;  // 0..255
    WpT[f * C_ + c] = (bf16_t)Wp[c * F_ + f];
}

// ---------------- pass 1: depthwise 3x3x3 conv, fp32 -> bf16 ----------------
// Fitted law (r1/r3/r6/r10): dur = requested_bytes / ~7.8 MB/us, invariant to
// width/occupancy/fences. r10 requests 6x unique bytes (4h/2h x 3w/1w).
// This round adds intra-thread w-pair reuse: thread = 2h x 2w x 8t x 4c,
// per (dh,tt) 4 w-column loads serve BOTH output columns -> amp 4 (-33%).
// Block = 64 c-lanes x 4 w-slots; covers h-pair x w-oct x full C. Grid 960.
__global__ __launch_bounds__(256, 2) void dw_conv_kernel(const float* __restrict__ x,
                                                         const float* __restrict__ Wd,
                                                         bf16_t* __restrict__ dw) {
    // XCD-chunked swizzle: grid 960 % 8 == 0 -> bijective
    int nchunk = gridDim.x >> 3;
    int bb  = (blockIdx.x & 7) * nchunk + (blockIdx.x >> 3);
    int h2  = bb / (W_ / 8);         // 0..47
    int wo  = bb % (W_ / 8);         // w-oct, 0..19
    int tid = threadIdx.x;
    int c   = (tid & 63) * 4;        // channel quad (64 lanes = full C)
    int s   = tid >> 6;              // w-slot, wave-uniform
    int h0  = h2 * 2;
    int w0  = wo * 8 + s * 2;        // output w-pair {w0, w0+1}

    // weights: compiler may keep resident or re-read from L1 (proven ~free, r3)
    f32x4 wreg[27];
#pragma unroll
    for (int k = 0; k < 27; ++k) wreg[k] = *(const f32x4*)&Wd[k * C_ + c];

    f32x4 acc[2][2][8] = {};         // [j(h)][iw][t]  = 128 VGPRs
    const int tstride = H_ * W_ * C_;
    const bool hasL = (w0 > 0);          // wave-uniform
    const bool hasR = (w0 + 2 < W_);     // wave-uniform

#pragma unroll
    for (int dh = -1; dh <= 2; ++dh) {
        int hh = h0 + dh;
        if (hh < 0 || hh >= H_) continue;          // block-uniform

        const float* pr = x + ((hh * W_ + w0) * C_ + c);
#pragma unroll
        for (int tt = 0; tt < 8; ++tt) {
            const float* pt = pr + tt * tstride;
            f32x4 v0, v3;
            if (hasL) v0 = *(const f32x4*)(pt - C_); else v0 = f32x4{};
            f32x4 v1 = *(const f32x4*)(pt);
            f32x4 v2 = *(const f32x4*)(pt + C_);
            if (hasR) v3 = *(const f32x4*)(pt + 2 * C_); else v3 = f32x4{};

#pragma unroll
            for (int j = 0; j < 2; ++j) {
                int kh = dh + 1 - j;
                if (kh < 0 || kh > 2) continue;    // compile-time
#pragma unroll
                for (int kt = 0; kt < 3; ++kt) {
                    int to = tt + 1 - kt;
                    if (to < 0 || to >= 8) continue;  // compile-time
                    f32x4 wA = wreg[(kt * 3 + kh) * 3 + 0];
                    f32x4 wB = wreg[(kt * 3 + kh) * 3 + 1];
                    f32x4 wC = wreg[(kt * 3 + kh) * 3 + 2];
                    acc[j][0][to] += v0 * wA + v1 * wB + v2 * wC;
                    acc[j][1][to] += v1 * wA + v2 * wB + v3 * wC;
                }
            }
        }
    }

#pragma unroll
    for (int j = 0; j < 2; ++j)
#pragma unroll
        for (int iw = 0; iw < 2; ++iw)
#pragma unroll
            for (int tt = 0; tt < 8; ++tt) {
                bf16x4 o;
#pragma unroll
                for (int q = 0; q < 4; ++q) o[q] = (bf16_t)acc[j][iw][tt][q];
                *(bf16x4*)&dw[((tt * H_ + (h0 + j)) * W_ + (w0 + iw)) * C_ + c] = o;
            }
}

// ---------------- pass 2: GEMM [M,256]x[256,256] bf16 MFMA + ReLU ----------------
#define BM 128
#define BN 128
#define BK 32
#define LDSTR 40  // 32 + 8 pad: fragment ds_read_b128 2-way (free) instead of 8-way

__global__ __launch_bounds__(256) void gemm_kernel(const bf16_t* __restrict__ A,   // dw  [M][C]
                                                   const bf16_t* __restrict__ Bt,  // WpT [F][C] (n-major)
                                                   float* __restrict__ out) {      // [M][F]
    __shared__ __align__(16) bf16_t As[BM * LDSTR];
    __shared__ __align__(16) bf16_t Bs[BN * LDSTR];

    int m0   = blockIdx.x * BM;
    int n0   = blockIdx.y * BN;
    int tid  = threadIdx.x;
    int lane = tid & 63;
    int wid  = tid >> 6;
    int wr   = wid >> 1;   // 0..1
    int wc   = wid & 1;    // 0..1
    int r16  = lane & 15;
    int kg   = lane >> 4;  // 0..3

    f32x4 acc[4][4] = {};

    for (int k0 = 0; k0 < C_; k0 += BK) {
        __syncthreads();
#pragma unroll
        for (int it = 0; it < 2; ++it) {
            int slot = tid + it * 256;       // 0..511
            int row  = slot >> 2;            // 0..127
            int seg  = slot & 3;             // 0..3 (8 bf16 each)
            uint4 va = *(const uint4*)&A[(long)(m0 + row) * C_ + k0 + seg * 8];
            *(uint4*)&As[row * LDSTR + seg * 8] = va;
            uint4 vb = *(const uint4*)&Bt[(n0 + row) * C_ + k0 + seg * 8];
            *(uint4*)&Bs[row * LDSTR + seg * 8] = vb;
        }
        __syncthreads();

        bf16x8 af[4], bfr[4];
#pragma unroll
        for (int m = 0; m < 4; ++m)
            af[m] = *(const bf16x8*)&As[(wr * 64 + m * 16 + r16) * LDSTR + kg * 8];
#pragma unroll
        for (int n = 0; n < 4; ++n)
            bfr[n] = *(const bf16x8*)&Bs[(wc * 64 + n * 16 + r16) * LDSTR + kg * 8];

#pragma unroll
        for (int m = 0; m < 4; ++m)
#pragma unroll
            for (int n = 0; n < 4; ++n)
                acc[m][n] = __builtin_amdgcn_mfma_f32_16x16x32_bf16(af[m], bfr[n], acc[m][n], 0, 0, 0);
    }

    // epilogue: ReLU + fp32 store.  D layout: row=(l>>4)*4+r, col=l&15
    int rbase = m0 + wr * 64 + kg * 4;
    int cbase = n0 + wc * 64 + r16;
#pragma unroll
    for (int m = 0; m < 4; ++m)
#pragma unroll
        for (int n = 0; n < 4; ++n)
#pragma unroll
            for (int r = 0; r < 4; ++r) {
                float v = acc[m][n][r];
                v = v > 0.f ? v : 0.f;
                out[(long)(rbase + m * 16 + r) * F_ + cbase + n * 16] = v;
            }
}

extern "C" void kernel_launch(void* const* d_in, const int* in_sizes, int n_in,
                              void* d_out, int out_size, void* d_ws, size_t ws_size,
                              hipStream_t stream) {
    const float* x  = (const float*)d_in[0];
    const float* Wd = (const float*)d_in[1];
    const float* Wp = (const float*)d_in[2];
    float* out = (float*)d_out;

    bf16_t* dw  = (bf16_t*)d_ws;                                  // M_*C_ bf16 = 62,914,560 B
    bf16_t* WpT = (bf16_t*)((char*)d_ws + (size_t)M_ * C_ * 2);   // + 131,072 B

    wp_transpose_kernel<<<C_, F_, 0, stream>>>(Wp, WpT);
    dw_conv_kernel<<<(H_ / 2) * (W_ / 8), 256, 0, stream>>>(x, Wd, dw);
    gemm_kernel<<<dim3(M_ / BM, F_ / BN), 256, 0, stream>>>(dw, WpT, out);
}

// Round 15
// 116.986 us; speedup vs baseline: 1.8186x; 1.8186x over previous
//
#include <hip/hip_runtime.h>
#include <hip/hip_bf16.h>

#define T_ 8
#define H_ 96
#define W_ 160
#define C_ 256
#define F_ 256
#define M_ (T_ * H_ * W_)   // 122880

typedef __bf16 bf16_t;
typedef __bf16 bf16x2 __attribute__((ext_vector_type(2)));
typedef __bf16 bf16x8 __attribute__((ext_vector_type(8)));
typedef float  f32x2  __attribute__((ext_vector_type(2)));
typedef float  f32x4  __attribute__((ext_vector_type(4)));

// ---------------- pass 0: WpT[f][c] = bf16(Wp[c][f]) ----------------
__global__ void wp_transpose_kernel(const float* __restrict__ Wp,
                                    bf16_t* __restrict__ WpT) {
    int c = blockIdx.x;   // 0..255
    int f = threadIdx.x;  // 0..255
    WpT[f * C_ + c] = (bf16_t)Wp[c * F_ + f];
}

// ---------------- pass 1: depthwise 3x3x3, rolling h-strip ----------------
// Byte-law (r1/r3/r6/r10): dur = requested_bytes / ~8 MB/us. This kernel cuts
// amp 6x -> 3.75x: thread = (c-pair, w) walks 10 h-planes for 8 h-outputs.
// Each plane: 24 f32x2 loads (3w x 8t), feeds 3 pending h-outputs (rolling
// acc, retired when complete). Regs: acc 48 + v 48 + wreg 54 + addr ~20 = 170.
// All acc indices literal via PLANE(I) macro; boundary planes zero-fill
// (block-uniform guards on loads only) so the init/accumulate pattern is
// static. No LDS, no barriers. Grid 1920 (12 strips x 160 w), 128-thr blocks.

#define PLANE(I)                                                              \
  {                                                                           \
    const int hh = h0 + (I) - 1;                                              \
    f32x2 v[3][8];                                                            \
    _Pragma("unroll") for (int kw = 0; kw < 3; ++kw)                          \
      _Pragma("unroll") for (int tt = 0; tt < 8; ++tt) v[kw][tt] = f32x2{};   \
    if (hh >= 0 && hh < H_) {            /* block-uniform */                  \
      const float* pb = x + (((long)hh * W_ + w) * C_ + c);                   \
      _Pragma("unroll") for (int tt = 0; tt < 8; ++tt)                        \
        v[1][tt] = *(const f32x2*)(pb + (long)tt * tstride);                  \
      if (hasL) {                                                             \
        _Pragma("unroll") for (int tt = 0; tt < 8; ++tt)                      \
          v[0][tt] = *(const f32x2*)(pb - C_ + (long)tt * tstride);           \
      }                                                                       \
      if (hasR) {                                                             \
        _Pragma("unroll") for (int tt = 0; tt < 8; ++tt)                      \
          v[2][tt] = *(const f32x2*)(pb + C_ + (long)tt * tstride);           \
      }                                                                       \
    }                                                                         \
    _Pragma("unroll") for (int kh = 0; kh < 3; ++kh) {                        \
      const int ko = (I) - kh;           /* literal after unroll */           \
      if (ko >= 0 && ko <= 7) {                                               \
        _Pragma("unroll") for (int to = 0; to < 8; ++to) {                    \
          f32x2 sum = f32x2{};                                                \
          _Pragma("unroll") for (int kt = 0; kt < 3; ++kt) {                  \
            const int ti = to + kt - 1;                                       \
            if (ti >= 0 && ti < 8) {                                          \
              _Pragma("unroll") for (int kw = 0; kw < 3; ++kw)                \
                sum += v[kw][ti] * wreg[(kt * 3 + kh) * 3 + kw];              \
            }                                                                 \
          }                                                                   \
          if (kh == 0) acc[ko][to] = sum; else acc[ko][to] += sum;            \
        }                                                                     \
      }                                                                       \
    }                                                                         \
    const int kd = (I) - 2;                                                   \
    if (kd >= 0 && kd <= 7) {                                                 \
      _Pragma("unroll") for (int tt = 0; tt < 8; ++tt) {                      \
        bf16x2 o;                                                             \
        o[0] = (bf16_t)acc[kd][tt][0];                                        \
        o[1] = (bf16_t)acc[kd][tt][1];                                        \
        *(bf16x2*)&dw[(((long)tt * H_ + h0 + kd) * W_ + w) * C_ + c] = o;     \
      }                                                                       \
    }                                                                         \
  }

__global__ __launch_bounds__(128, 2) void dw_conv_kernel(const float* __restrict__ x,
                                                         const float* __restrict__ Wd,
                                                         bf16_t* __restrict__ dw) {
    // XCD-chunked swizzle: grid 1920 % 8 == 0 -> bijective
    int nchunk = gridDim.x >> 3;
    int bb  = (blockIdx.x & 7) * nchunk + (blockIdx.x >> 3);
    int hs  = bb / W_;               // strip, 0..11
    int w   = bb % W_;               // 0..159 (adjacent bb share w-halos)
    int h0  = hs * 8;
    int tid = threadIdx.x;           // 0..127
    int c   = tid * 2;               // channel pair (wave = 512B coalesced)

    const bool hasL = (w > 0);           // block-uniform
    const bool hasR = (w < W_ - 1);      // block-uniform
    const int tstride = H_ * W_ * C_;

    f32x2 wreg[27];
#pragma unroll
    for (int k = 0; k < 27; ++k) wreg[k] = *(const f32x2*)&Wd[k * C_ + c];

    f32x2 acc[8][8];                 // [h-out][t]; live window <= 3 h-sets

    PLANE(0) PLANE(1) PLANE(2) PLANE(3) PLANE(4)
    PLANE(5) PLANE(6) PLANE(7) PLANE(8) PLANE(9)
}

// ---------------- pass 2: GEMM [M,256]x[256,256] bf16 MFMA + ReLU ----------------
#define BM 128
#define BN 128
#define BK 32
#define LDSTR 40  // 32 + 8 pad: fragment ds_read_b128 2-way (free) instead of 8-way

__global__ __launch_bounds__(256) void gemm_kernel(const bf16_t* __restrict__ A,   // dw  [M][C]
                                                   const bf16_t* __restrict__ Bt,  // WpT [F][C] (n-major)
                                                   float* __restrict__ out) {      // [M][F]
    __shared__ __align__(16) bf16_t As[BM * LDSTR];
    __shared__ __align__(16) bf16_t Bs[BN * LDSTR];

    int m0   = blockIdx.x * BM;
    int n0   = blockIdx.y * BN;
    int tid  = threadIdx.x;
    int lane = tid & 63;
    int wid  = tid >> 6;
    int wr   = wid >> 1;   // 0..1
    int wc   = wid & 1;    // 0..1
    int r16  = lane & 15;
    int kg   = lane >> 4;  // 0..3

    f32x4 acc[4][4] = {};

    for (int k0 = 0; k0 < C_; k0 += BK) {
        __syncthreads();
#pragma unroll
        for (int it = 0; it < 2; ++it) {
            int slot = tid + it * 256;       // 0..511
            int row  = slot >> 2;            // 0..127
            int seg  = slot & 3;             // 0..3 (8 bf16 each)
            uint4 va = *(const uint4*)&A[(long)(m0 + row) * C_ + k0 + seg * 8];
            *(uint4*)&As[row * LDSTR + seg * 8] = va;
            uint4 vb = *(const uint4*)&Bt[(n0 + row) * C_ + k0 + seg * 8];
            *(uint4*)&Bs[row * LDSTR + seg * 8] = vb;
        }
        __syncthreads();

        bf16x8 af[4], bfr[4];
#pragma unroll
        for (int m = 0; m < 4; ++m)
            af[m] = *(const bf16x8*)&As[(wr * 64 + m * 16 + r16) * LDSTR + kg * 8];
#pragma unroll
        for (int n = 0; n < 4; ++n)
            bfr[n] = *(const bf16x8*)&Bs[(wc * 64 + n * 16 + r16) * LDSTR + kg * 8];

#pragma unroll
        for (int m = 0; m < 4; ++m)
#pragma unroll
            for (int n = 0; n < 4; ++n)
                acc[m][n] = __builtin_amdgcn_mfma_f32_16x16x32_bf16(af[m], bfr[n], acc[m][n], 0, 0, 0);
    }

    // epilogue: ReLU + fp32 store.  D layout: row=(l>>4)*4+r, col=l&15
    int rbase = m0 + wr * 64 + kg * 4;
    int cbase = n0 + wc * 64 + r16;
#pragma unroll
    for (int m = 0; m < 4; ++m)
#pragma unroll
        for (int n = 0; n < 4; ++n)
#pragma unroll
            for (int r = 0; r < 4; ++r) {
                float v = acc[m][n][r];
                v = v > 0.f ? v : 0.f;
                out[(long)(rbase + m * 16 + r) * F_ + cbase + n * 16] = v;
            }
}

extern "C" void kernel_launch(void* const* d_in, const int* in_sizes, int n_in,
                              void* d_out, int out_size, void* d_ws, size_t ws_size,
                              hipStream_t stream) {
    const float* x  = (const float*)d_in[0];
    const float* Wd = (const float*)d_in[1];
    const float* Wp = (const float*)d_in[2];
    float* out = (float*)d_out;

    bf16_t* dw  = (bf16_t*)d_ws;                                  // M_*C_ bf16 = 62,914,560 B
    bf16_t* WpT = (bf16_t*)((char*)d_ws + (size_t)M_ * C_ * 2);   // + 131,072 B

    wp_transpose_kernel<<<C_, F_, 0, stream>>>(Wp, WpT);
    dw_conv_kernel<<<(H_ / 8) * W_, 128, 0, stream>>>(x, Wd, dw);
    gemm_kernel<<<dim3(M_ / BM, F_ / BN), 256, 0, stream>>>(dw, WpT, out);
}